// Round 10
// baseline (1248.607 us; speedup 1.0000x reference)
//
#include <hip/hip_runtime.h>
#include <math.h>

// Problem constants (from reference)
#define TT 2048
#define BB 512
#define II 11
#define HH 33
#define NL 3
#define OO 18
#define HSLOT 48          // halves per LDS vector slot (96 B, 16B-aligned slots)

typedef _Float16 h2 __attribute__((ext_vector_type(2)));
typedef _Float16 h4 __attribute__((ext_vector_type(4)));
typedef _Float16 h8 __attribute__((ext_vector_type(8)));   // 16 B -> ds_read_b128

// fast sigmoid / tanh via v_exp_f32 + v_rcp_f32 (saturate correctly at +-inf)
__device__ __forceinline__ float sigm_f(float x) {
    float e = __expf(-x);
    return __builtin_amdgcn_rcpf(1.0f + e);
}
__device__ __forceinline__ float tanh_f(float x) {
    float e = __expf(2.0f * x);
    return 1.0f - 2.0f * __builtin_amdgcn_rcpf(e + 1.0f);
}

// DPP quad_perm [1,0,3,2]: exchange within adjacent lane pairs (VALU pipe, no LDS)
__device__ __forceinline__ float dpp_xor1(float v) {
    return __builtin_bit_cast(float,
        __builtin_amdgcn_update_dpp(0, __builtin_bit_cast(int, v), 0xB1, 0xF, 0xF, true));
}
__device__ __forceinline__ h2 dpp_xor1_h2(h2 v) {
    return __builtin_bit_cast(h2,
        __builtin_amdgcn_update_dpp(0, __builtin_bit_cast(int, v), 0xB1, 0xF, 0xF, true));
}

// guarded fp32->fp16 row-slice loads (zero-pad past rem)
__device__ __forceinline__ h8 gldh8(const float* p, int k0, int rem) {
    h8 v;
    #pragma unroll
    for (int i = 0; i < 8; ++i) v[i] = (_Float16)((k0 + i < rem) ? p[k0 + i] : 0.0f);
    return v;
}
__device__ __forceinline__ h4 gldh4(const float* p, int k0, int rem) {
    h4 v;
    #pragma unroll
    for (int i = 0; i < 4; ++i) v[i] = (_Float16)((k0 + i < rem) ? p[k0 + i] : 0.0f);
    return v;
}

// packed fp16 FMA (v_pk_fma_f16, full-rate: 2 cyc / 2 MACs vs fdot2's 4 cyc)
#define PF(acc, vv, ww) acc = __builtin_elementwise_fma((vv), (ww), (acc))
// one h8 chunk into two alternating h2 chains (keeps f16 add chains short)
#define PK8(A, B, v, w) do { \
    PF(A, (v).s01, (w).s01); PF(B, (v).s23, (w).s23); \
    PF(A, (v).s45, (w).s45); PF(B, (v).s67, (w).s67); } while (0)
#define PK4(A, B, v, w) do { \
    PF(A, (v).s01, (w).s01); PF(B, (v).s23, (w).s23); } while (0)

// Layer-pipelined LSTM: R9 structure (pair-split, peeled steady state) with
// the dots moved from v_dot2_f32_f16 (4 cyc / 2 MAC) to v_pk_fma_f16
// (2 cyc / 2 MAC, fp16 accumulate in 2 short chains per gate), and the MLP
// head fused into the epilogue (no 2nd dispatch).
// grid = 512 blocks (one batch element each), block = 256 threads (4 waves).
//   tid < 198 : u = tid>>1 (unit 0..98), p = tid&1 (role). l = u/33, j = u%33.
//     p=0: reads layer INPUT vector (slot l), holds the 4 W_ih gate rows.
//     p=1: reads OWN-h vector (slot l+1), holds the 4 W_hh gate rows.
//     72 pk_fma partial dots -> A+B combine (pk_add) -> pair all-reduce
//     (DPP mov + pk_add, packed) -> horizontal + bias in fp32 -> activation
//     dedupe (p0: i,f; p1: g,o via tanh(x)=2*sigm(2x)-1) -> c,h.
//   tid 198..208 : x prefetchers (11 features), 2-deep software pipeline.
// LDS: ping-pong buf[2][4][HSLOT] halves; one barrier per superstep.
__global__ __launch_bounds__(256, 2) void lstm_pipeline_kernel(
    const float* __restrict__ x,
    const float* __restrict__ Wih0, const float* __restrict__ Whh0,
    const float* __restrict__ bih0, const float* __restrict__ bhh0,
    const float* __restrict__ Wih1, const float* __restrict__ Whh1,
    const float* __restrict__ bih1, const float* __restrict__ bhh1,
    const float* __restrict__ Wih2, const float* __restrict__ Whh2,
    const float* __restrict__ bih2, const float* __restrict__ bhh2,
    const float* __restrict__ W1, const float* __restrict__ b1,
    const float* __restrict__ W2, const float* __restrict__ b2,
    float* __restrict__ hidden_out,   // [3, 512, 33]
    float* __restrict__ outp)         // [3, 512, 18]
{
    __shared__ __align__(16) _Float16 buf[2][NL + 1][HSLOT];
    __shared__ float hfin[NL][HH];      // final h per layer (fp32, for fused MLP)
    __shared__ float h1s[NL][4 * OO];   // MLP hidden

    const int tid = threadIdx.x;
    const int bg  = blockIdx.x;

    for (int i = tid; i < 2 * (NL + 1) * HSLOT; i += 256)
        ((_Float16*)buf)[i] = (_Float16)0.0f;

    const bool comp = (tid < 198);
    const int  u    = tid >> 1;          // unit 0..98
    const int  p    = tid & 1;           // 0 = input-role, 1 = h-role
    const int  l    = (u < 33) ? 0 : (u < 66) ? 1 : 2;
    const int  j    = u - 33 * l;

    const int  pi   = tid - 198;
    const bool pref = (pi >= 0) && (pi < II);
    const float* xrow = x + (size_t)bg * TT * II + (pref ? pi : 0);

    // ---- per-lane weights: 4 gate rows x 36 cols, packed fp16 = 36 VGPRs ----
    h8 z8 = {0,0,0,0,0,0,0,0};
    h4 z4 = {0,0,0,0};
    h8 w0a=z8,w0b=z8,w0c=z8,w0d=z8; h4 w0t=z4;   // gate i
    h8 w1a=z8,w1b=z8,w1c=z8,w1d=z8; h4 w1t=z4;   // gate f
    h8 w2a=z8,w2b=z8,w2c=z8,w2d=z8; h4 w2t=z4;   // gate g
    h8 w3a=z8,w3b=z8,w3c=z8,w3d=z8; h4 w3t=z4;   // gate o
    float b0 = 0.0f, b1v = 0.0f, b2v = 0.0f, b3v = 0.0f;

    if (comp) {
        const float* bip = (l == 0) ? bih0 : (l == 1) ? bih1 : bih2;
        const float* bhp = (l == 0) ? bhh0 : (l == 1) ? bhh1 : bhh2;
        // bias now added POST-reduce, so BOTH lanes carry the full bias
        b0  = bip[0 * HH + j] + bhp[0 * HH + j];
        b1v = bip[1 * HH + j] + bhp[1 * HH + j];
        b2v = bip[2 * HH + j] + bhp[2 * HH + j];
        b3v = bip[3 * HH + j] + bhp[3 * HH + j];

        const float* Wsrc = p ? ((l == 0) ? Whh0 : (l == 1) ? Whh1 : Whh2)
                              : ((l == 0) ? Wih0 : (l == 1) ? Wih1 : Wih2);
        const int kin = (p || l != 0) ? HH : II;
        const float* r0 = Wsrc + (0 * HH + j) * kin;
        const float* r1 = Wsrc + (1 * HH + j) * kin;
        const float* r2 = Wsrc + (2 * HH + j) * kin;
        const float* r3 = Wsrc + (3 * HH + j) * kin;
        w0a = gldh8(r0, 0, kin); w0b = gldh8(r0, 8, kin);
        w0c = gldh8(r0, 16, kin); w0d = gldh8(r0, 24, kin); w0t = gldh4(r0, 32, kin);
        w1a = gldh8(r1, 0, kin); w1b = gldh8(r1, 8, kin);
        w1c = gldh8(r1, 16, kin); w1d = gldh8(r1, 24, kin); w1t = gldh4(r1, 32, kin);
        w2a = gldh8(r2, 0, kin); w2b = gldh8(r2, 8, kin);
        w2c = gldh8(r2, 16, kin); w2d = gldh8(r2, 24, kin); w2t = gldh4(r2, 32, kin);
        w3a = gldh8(r3, 0, kin); w3b = gldh8(r3, 8, kin);
        w3c = gldh8(r3, 16, kin); w3d = gldh8(r3, 24, kin); w3t = gldh4(r3, 32, kin);
    }

    __syncthreads();
    float v_next = 0.0f, v_next2 = 0.0f;
    if (pref) {
        buf[0][0][pi] = (_Float16)xrow[0];
        v_next  = xrow[II];
        v_next2 = xrow[2 * II];
    }
    __syncthreads();

    float c = 0.0f;
    const int   vsel = p ? (l + 1) : l;      // which LDS slot this lane reads
    const float mA   = 1.0f + (float)p;      // activation-a: 1 -> sigm, 2 -> tanh
    const float cAc  = -(float)p;
    const bool  wrh  = comp && (p == 0);     // h-writer lanes

    // hoisted ping-pong pointers (compile-time selected in peeled steps)
    const _Float16* rd[2]  = { &buf[0][vsel][0], &buf[1][vsel][0] };
    _Float16*       wrp[2] = { &buf[0][l + 1][j], &buf[1][l + 1][j] };
    _Float16*       pxp[2] = { &buf[0][0][pi], &buf[1][0][pi] };

    // one superstep; all bool/int args are compile-time constants at call sites
    auto step = [&](int s, int rp, bool check, bool out, bool xload, bool xstore)
        __attribute__((always_inline)) {
        const int wp = rp ^ 1;
        if (pref) {
            if (xstore) *pxp[wp] = (_Float16)v_next;
            v_next = v_next2;
            if (xload) v_next2 = xrow[(size_t)(s + 3) * II];
        }
        const bool active = check ? (comp && (s >= l) && (s - l < TT)) : comp;
        if (active) {
            const _Float16* V16 = rd[rp];
            const h8* V = (const h8*)V16;
            const h8 v0 = V[0], v1 = V[1], v2 = V[2], v3 = V[3];
            const h4 vt = *(const h4*)(V16 + 32);

            // 72 v_pk_fma_f16: 2 chains of 9 per gate (fp16 accumulate)
            h2 z2 = {(_Float16)0.0f, (_Float16)0.0f};
            h2 A0 = z2, B0 = z2, A1 = z2, B1 = z2;
            h2 A2 = z2, B2 = z2, A3 = z2, B3 = z2;
            PK8(A0, B0, v0, w0a); PK8(A1, B1, v0, w1a);
            PK8(A2, B2, v0, w2a); PK8(A3, B3, v0, w3a);
            PK8(A0, B0, v1, w0b); PK8(A1, B1, v1, w1b);
            PK8(A2, B2, v1, w2b); PK8(A3, B3, v1, w3b);
            PK8(A0, B0, v2, w0c); PK8(A1, B1, v2, w1c);
            PK8(A2, B2, v2, w2c); PK8(A3, B3, v2, w3c);
            PK8(A0, B0, v3, w0d); PK8(A1, B1, v3, w1d);
            PK8(A2, B2, v3, w2d); PK8(A3, B3, v3, w3d);
            PK4(A0, B0, vt, w0t); PK4(A1, B1, vt, w1t);
            PK4(A2, B2, vt, w2t); PK4(A3, B3, vt, w3t);

            // combine chains (v_pk_add_f16), then pair all-reduce packed
            h2 t0 = A0 + B0, t1 = A1 + B1, t2 = A2 + B2, t3 = A3 + B3;
            t0 += dpp_xor1_h2(t0); t1 += dpp_xor1_h2(t1);
            t2 += dpp_xor1_h2(t2); t3 += dpp_xor1_h2(t3);

            // horizontal + bias in fp32 (both lanes hold full bias)
            const float a0 = b0  + ((float)t0.x + (float)t0.y);
            const float a1 = b1v + ((float)t1.x + (float)t1.y);
            const float a2 = b2v + ((float)t2.x + (float)t2.y);
            const float a3 = b3v + ((float)t3.x + (float)t3.y);

            // activation dedupe: p0 activates i,f; p1 activates g,o
            const float aA = p ? a2 : a0;
            const float aB = p ? a3 : a1;
            const float acta = __builtin_fmaf(mA, sigm_f(mA * aA), cAc); // i or g
            const float actb = sigm_f(aB);                               // f or o
            const float xa = dpp_xor1(acta);
            const float xb = dpp_xor1(actb);
            const float ig = p ? xa : acta;
            const float gg = p ? acta : xa;
            const float fg = p ? xb : actb;
            const float og = p ? actb : xb;

            c = __builtin_fmaf(fg, c, ig * gg);   // identical in both lanes (fp32)
            const float hnew = og * tanh_f(c);

            if (wrh) {
                *wrp[wp] = (_Float16)hnew;
                if (out && (s - l == TT - 1)) {
                    hidden_out[((size_t)l * BB + bg) * HH + j] = hnew;
                    hfin[l][j] = hnew;
                }
            }
        }
        __syncthreads();
    };

    // prologue (pipeline fill, masked)
    step(0, 0, true, false, true, true);
    step(1, 1, true, false, true, true);
    // steady state: s = 2..2043 as constant-rp pairs (no checks, no outputs)
    for (int s = 2; s < TT - 4; s += 2) {
        step(s,     0, false, false, true, true);
        step(s + 1, 1, false, false, true, true);
    }
    // tail of steady state + epilogue (drain + final-h outputs)
    step(TT - 4, 0, false, false, true,  true);    // s=2044 (last x load)
    step(TT - 3, 1, false, false, false, true);    // s=2045
    step(TT - 2, 0, false, false, false, true);    // s=2046 (stores x[2047])
    step(TT - 1, 1, false, true,  false, false);   // s=2047: l0 writes hT
    step(TT,     0, true,  true,  false, false);   // s=2048: l1 writes hT
    step(TT + 1, 1, true,  true,  false, false);   // s=2049: l2 writes hT

    // ---- fused MLP head (hfin visible after the last step's barrier) ----
    // h1 = gelu_exact(hfin @ W1^T + b1) [3,72]; out = h1 @ W2^T + b2 [3,18]
    if (tid < NL * 4 * OO) {             // 216 threads
        const int ml = tid / (4 * OO), m = tid % (4 * OO);
        float a = b1[m];
        #pragma unroll
        for (int k = 0; k < HH; ++k) a += hfin[ml][k] * W1[m * HH + k];
        h1s[ml][m] = 0.5f * a * (1.0f + erff(a * 0.70710678118654752f));
    }
    __syncthreads();
    if (tid < NL * OO) {                 // 54 threads
        const int ol = tid / OO, o = tid % OO;
        float a = b2[o];
        #pragma unroll
        for (int m = 0; m < 4 * OO; ++m) a += h1s[ol][m] * W2[o * (4 * OO) + m];
        outp[((size_t)ol * BB + bg) * OO + o] = a;
    }
}

extern "C" void kernel_launch(void* const* d_in, const int* in_sizes, int n_in,
                              void* d_out, int out_size, void* d_ws, size_t ws_size,
                              hipStream_t stream) {
    const float* x    = (const float*)d_in[0];
    const float* Wih0 = (const float*)d_in[1];
    const float* Whh0 = (const float*)d_in[2];
    const float* bih0 = (const float*)d_in[3];
    const float* bhh0 = (const float*)d_in[4];
    const float* Wih1 = (const float*)d_in[5];
    const float* Whh1 = (const float*)d_in[6];
    const float* bih1 = (const float*)d_in[7];
    const float* bhh1 = (const float*)d_in[8];
    const float* Wih2 = (const float*)d_in[9];
    const float* Whh2 = (const float*)d_in[10];
    const float* bih2 = (const float*)d_in[11];
    const float* bhh2 = (const float*)d_in[12];
    const float* W1   = (const float*)d_in[13];
    const float* b1   = (const float*)d_in[14];
    const float* W2   = (const float*)d_in[15];
    const float* b2   = (const float*)d_in[16];

    float* out    = (float*)d_out;                 // [3,512,18] = 27648 floats
    float* hidden = out + NL * BB * OO;            // [3,512,33] = 50688 floats

    lstm_pipeline_kernel<<<BB, 256, 0, stream>>>(
        x, Wih0, Whh0, bih0, bhh0, Wih1, Whh1, bih1, bhh1,
        Wih2, Whh2, bih2, bhh2, W1, b1, W2, b2, hidden, out);
}

// Round 11
// 1149.650 us; speedup vs baseline: 1.0861x; 1.0861x over previous
//
#include <hip/hip_runtime.h>
#include <math.h>

// Problem constants (from reference)
#define TT 2048
#define BB 512
#define II 11
#define HH 33
#define NL 3
#define OO 18
#define HSLOT 48          // halves per LDS vector slot (96 B, 16B-aligned slots)

typedef _Float16 h2 __attribute__((ext_vector_type(2)));
typedef _Float16 h8 __attribute__((ext_vector_type(8)));   // 16 B -> ds_read_b128

// fast sigmoid / tanh via v_exp_f32 + v_rcp_f32 (saturate correctly at +-inf)
__device__ __forceinline__ float sigm_f(float x) {
    float e = __expf(-x);
    return __builtin_amdgcn_rcpf(1.0f + e);
}
__device__ __forceinline__ float tanh_f(float x) {
    float e = __expf(2.0f * x);
    return 1.0f - 2.0f * __builtin_amdgcn_rcpf(e + 1.0f);
}

// guarded fp32->fp16 row-slice loads (zero-pad past rem)
__device__ __forceinline__ h8 gldh8(const float* p, int k0, int rem) {
    h8 v;
    #pragma unroll
    for (int i = 0; i < 8; ++i) v[i] = (_Float16)((k0 + i < rem) ? p[k0 + i] : 0.0f);
    return v;
}
__device__ __forceinline__ h2 gldh2(const float* p, int k0, int rem) {
    h2 v;
    v.x = (_Float16)((k0 + 0 < rem) ? p[k0 + 0] : 0.0f);
    v.y = (_Float16)((k0 + 1 < rem) ? p[k0 + 1] : 0.0f);
    return v;
}

// v_dot2_f32_f16 chains: 2 MACs/op, fp32 accumulate
#define D8(a, v, w) do { \
    a = __builtin_amdgcn_fdot2((v).s01, (w).s01, a, false); \
    a = __builtin_amdgcn_fdot2((v).s23, (w).s23, a, false); \
    a = __builtin_amdgcn_fdot2((v).s45, (w).s45, a, false); \
    a = __builtin_amdgcn_fdot2((v).s67, (w).s67, a, false); } while (0)
#define D1(a, v, w) a = __builtin_amdgcn_fdot2((v), (w), a, false)

// Layer-pipelined LSTM, ONE LANE PER UNIT (no cross-lane ops at all).
// grid = 512 blocks (one batch element each), block = 128 threads (2 waves).
//   tid < 99 : unit u = tid, l = u/33, j = u%33. The lane holds ALL weights of
//   its unit (4 gate rows x (input 34 + own-h 34) halves = 136 VGPRs packed),
//   reads the layer-input vector (slot l) and own-h vector (slot l+1) from
//   LDS (broadcast reads), runs 136 fdot2 in 4 interleaved chains, then the
//   full gate nonlinearity and c/h update locally. h written as one b16.
//   tid 99..109 : x prefetchers (11 features), 2-deep software pipeline.
// Rationale (R4-R10 calibration): ALL VALU MAC paths are 0.5 MAC/lane/cyc, so
// dot issue per SIMD is fixed; 1 lane/unit removes the pair-reduce/redistribute
// and halves the per-unit scaffolding stream. Cost: 1 wave/SIMD (no TLP) --
// mitigated by 2-wave blocks (small barrier skew) and 4-chain ILP.
// LDS: ping-pong buf[2][4][HSLOT] halves; one barrier per superstep; peeled
// steady state with compile-time ping-pong (R9 scheme).
__global__ __launch_bounds__(128, 1) void lstm_pipeline_kernel(
    const float* __restrict__ x,
    const float* __restrict__ Wih0, const float* __restrict__ Whh0,
    const float* __restrict__ bih0, const float* __restrict__ bhh0,
    const float* __restrict__ Wih1, const float* __restrict__ Whh1,
    const float* __restrict__ bih1, const float* __restrict__ bhh1,
    const float* __restrict__ Wih2, const float* __restrict__ Whh2,
    const float* __restrict__ bih2, const float* __restrict__ bhh2,
    float* __restrict__ hidden_out)   // [3, 512, 33]
{
    __shared__ __align__(16) _Float16 buf[2][NL + 1][HSLOT];

    const int tid = threadIdx.x;
    const int bg  = blockIdx.x;

    for (int i = tid; i < 2 * (NL + 1) * HSLOT; i += 128)
        ((_Float16*)buf)[i] = (_Float16)0.0f;

    const bool comp = (tid < 99);
    const int  u    = tid;
    const int  l    = (u < 33) ? 0 : (u < 66) ? 1 : 2;
    const int  j    = u - 33 * l;

    const int  pi   = tid - 99;
    const bool pref = (pi >= 0) && (pi < II);
    const float* xrow = x + (size_t)bg * TT * II + (pref ? pi : 0);

    // ---- per-lane weights: 4 gates x (input 34 + own 34) halves, named regs ----
    h8 z8 = {0,0,0,0,0,0,0,0};
    h2 z2 = {(_Float16)0.0f, (_Float16)0.0f};
    h8 x00=z8,x01=z8,x02=z8,x03=z8; h2 x0t=z2;   // gate i, input side (W_ih row)
    h8 x10=z8,x11=z8,x12=z8,x13=z8; h2 x1t=z2;   // gate f
    h8 x20=z8,x21=z8,x22=z8,x23=z8; h2 x2t=z2;   // gate g
    h8 x30=z8,x31=z8,x32=z8,x33=z8; h2 x3t=z2;   // gate o
    h8 h00=z8,h01=z8,h02=z8,h03=z8; h2 h0t=z2;   // gate i, own-h side (W_hh row)
    h8 h10=z8,h11=z8,h12=z8,h13=z8; h2 h1t=z2;
    h8 h20=z8,h21=z8,h22=z8,h23=z8; h2 h2t=z2;
    h8 h30=z8,h31=z8,h32=z8,h33=z8; h2 h3t=z2;
    float b0 = 0.0f, b1 = 0.0f, b2 = 0.0f, b3 = 0.0f;

    if (comp) {
        const float* bip = (l == 0) ? bih0 : (l == 1) ? bih1 : bih2;
        const float* bhp = (l == 0) ? bhh0 : (l == 1) ? bhh1 : bhh2;
        b0 = bip[0 * HH + j] + bhp[0 * HH + j];
        b1 = bip[1 * HH + j] + bhp[1 * HH + j];
        b2 = bip[2 * HH + j] + bhp[2 * HH + j];
        b3 = bip[3 * HH + j] + bhp[3 * HH + j];

        const float* Wi = (l == 0) ? Wih0 : (l == 1) ? Wih1 : Wih2;
        const float* Wh = (l == 0) ? Whh0 : (l == 1) ? Whh1 : Whh2;
        const int kin = (l == 0) ? II : HH;
        const float* r0 = Wi + (0 * HH + j) * kin;
        const float* r1 = Wi + (1 * HH + j) * kin;
        const float* r2 = Wi + (2 * HH + j) * kin;
        const float* r3 = Wi + (3 * HH + j) * kin;
        x00=gldh8(r0,0,kin); x01=gldh8(r0,8,kin); x02=gldh8(r0,16,kin); x03=gldh8(r0,24,kin); x0t=gldh2(r0,32,kin);
        x10=gldh8(r1,0,kin); x11=gldh8(r1,8,kin); x12=gldh8(r1,16,kin); x13=gldh8(r1,24,kin); x1t=gldh2(r1,32,kin);
        x20=gldh8(r2,0,kin); x21=gldh8(r2,8,kin); x22=gldh8(r2,16,kin); x23=gldh8(r2,24,kin); x2t=gldh2(r2,32,kin);
        x30=gldh8(r3,0,kin); x31=gldh8(r3,8,kin); x32=gldh8(r3,16,kin); x33=gldh8(r3,24,kin); x3t=gldh2(r3,32,kin);
        const float* s0 = Wh + (0 * HH + j) * HH;
        const float* s1 = Wh + (1 * HH + j) * HH;
        const float* s2 = Wh + (2 * HH + j) * HH;
        const float* s3 = Wh + (3 * HH + j) * HH;
        h00=gldh8(s0,0,HH); h01=gldh8(s0,8,HH); h02=gldh8(s0,16,HH); h03=gldh8(s0,24,HH); h0t=gldh2(s0,32,HH);
        h10=gldh8(s1,0,HH); h11=gldh8(s1,8,HH); h12=gldh8(s1,16,HH); h13=gldh8(s1,24,HH); h1t=gldh2(s1,32,HH);
        h20=gldh8(s2,0,HH); h21=gldh8(s2,8,HH); h22=gldh8(s2,16,HH); h23=gldh8(s2,24,HH); h2t=gldh2(s2,32,HH);
        h30=gldh8(s3,0,HH); h31=gldh8(s3,8,HH); h32=gldh8(s3,16,HH); h33=gldh8(s3,24,HH); h3t=gldh2(s3,32,HH);
    }

    __syncthreads();
    float v_next = 0.0f, v_next2 = 0.0f;
    if (pref) {
        buf[0][0][pi] = (_Float16)xrow[0];
        v_next  = xrow[II];
        v_next2 = xrow[2 * II];
    }
    __syncthreads();

    float c = 0.0f;

    // hoisted ping-pong pointers (compile-time selected in peeled steps)
    const _Float16* rin[2]  = { &buf[0][l][0],     &buf[1][l][0] };      // input vec
    const _Float16* rown[2] = { &buf[0][l + 1][0], &buf[1][l + 1][0] };  // own-h vec
    _Float16*       wrp[2]  = { &buf[0][l + 1][j], &buf[1][l + 1][j] };
    _Float16*       pxp[2]  = { &buf[0][0][pi],    &buf[1][0][pi] };

    // one superstep; all bool/int args are compile-time constants at call sites
    auto step = [&](int s, int rp, bool check, bool out, bool xload, bool xstore)
        __attribute__((always_inline)) {
        const int wp = rp ^ 1;
        if (pref) {
            if (xstore) *pxp[wp] = (_Float16)v_next;
            v_next = v_next2;
            if (xload) v_next2 = xrow[(size_t)(s + 3) * II];
        }
        const bool active = check ? (comp && (s >= l) && (s - l < TT)) : comp;
        if (active) {
            const h8* VI = (const h8*)rin[rp];
            const h8 vi0 = VI[0], vi1 = VI[1], vi2 = VI[2], vi3 = VI[3];
            const h2 vit = *(const h2*)(rin[rp] + 32);
            const h8* VO = (const h8*)rown[rp];
            const h8 vo0 = VO[0], vo1 = VO[1], vo2 = VO[2], vo3 = VO[3];
            const h2 vot = *(const h2*)(rown[rp] + 32);

            // 136 fdot2 in 4 independent chains, interleaved for ILP
            float a0 = b0, a1 = b1, a2 = b2, a3 = b3;
            D8(a0, vi0, x00); D8(a1, vi0, x10); D8(a2, vi0, x20); D8(a3, vi0, x30);
            D8(a0, vi1, x01); D8(a1, vi1, x11); D8(a2, vi1, x21); D8(a3, vi1, x31);
            D8(a0, vi2, x02); D8(a1, vi2, x12); D8(a2, vi2, x22); D8(a3, vi2, x32);
            D8(a0, vi3, x03); D8(a1, vi3, x13); D8(a2, vi3, x23); D8(a3, vi3, x33);
            D1(a0, vit, x0t); D1(a1, vit, x1t); D1(a2, vit, x2t); D1(a3, vit, x3t);
            D8(a0, vo0, h00); D8(a1, vo0, h10); D8(a2, vo0, h20); D8(a3, vo0, h30);
            D8(a0, vo1, h01); D8(a1, vo1, h11); D8(a2, vo1, h21); D8(a3, vo1, h31);
            D8(a0, vo2, h02); D8(a1, vo2, h12); D8(a2, vo2, h22); D8(a3, vo2, h32);
            D8(a0, vo3, h03); D8(a1, vo3, h13); D8(a2, vo3, h23); D8(a3, vo3, h33);
            D1(a0, vot, h0t); D1(a1, vot, h1t); D1(a2, vot, h2t); D1(a3, vot, h3t);

            // full gate nonlinearity, all local (no cross-lane ops)
            const float ig = sigm_f(a0);
            const float fg = sigm_f(a1);
            const float gg = tanh_f(a2);
            const float og = sigm_f(a3);
            c = __builtin_fmaf(fg, c, ig * gg);
            const float hnew = og * tanh_f(c);

            *wrp[wp] = (_Float16)hnew;
            if (out && (s - l == TT - 1))
                hidden_out[((size_t)l * BB + bg) * HH + j] = hnew;
        }
        __syncthreads();
    };

    // prologue (pipeline fill, masked)
    step(0, 0, true, false, true, true);
    step(1, 1, true, false, true, true);
    // steady state: s = 2..2043 as constant-rp pairs (no checks, no outputs)
    for (int s = 2; s < TT - 4; s += 2) {
        step(s,     0, false, false, true, true);
        step(s + 1, 1, false, false, true, true);
    }
    // tail of steady state + epilogue (drain + final-h outputs)
    step(TT - 4, 0, false, false, true,  true);    // s=2044 (last x load)
    step(TT - 3, 1, false, false, false, true);    // s=2045
    step(TT - 2, 0, false, false, false, true);    // s=2046 (stores x[2047])
    step(TT - 1, 1, false, true,  false, false);   // s=2047: l0 writes hT
    step(TT,     0, true,  true,  false, false);   // s=2048: l1 writes hT
    step(TT + 1, 1, true,  true,  false, false);   // s=2049: l2 writes hT
}

// MLP head: hidden [3*512, 33] -> gelu(hidden@W1^T + b1) [.,72] -> @W2^T + b2 [.,18]
__global__ void mlp_head_kernel(const float* __restrict__ hidden,
                                const float* __restrict__ W1, const float* __restrict__ b1,
                                const float* __restrict__ W2, const float* __restrict__ b2,
                                float* __restrict__ out)
{
    const int row = blockIdx.x * blockDim.x + threadIdx.x;   // 0..1535
    if (row >= NL * BB) return;

    float hv[HH];
    #pragma unroll
    for (int k = 0; k < HH; ++k) hv[k] = hidden[row * HH + k];

    float h1[4 * OO];
    #pragma unroll
    for (int m = 0; m < 4 * OO; ++m) {
        float a = b1[m];
        #pragma unroll
        for (int k = 0; k < HH; ++k) a += hv[k] * W1[m * HH + k];
        h1[m] = 0.5f * a * (1.0f + erff(a * 0.70710678118654752f));
    }
    #pragma unroll
    for (int o = 0; o < OO; ++o) {
        float a = b2[o];
        #pragma unroll
        for (int m = 0; m < 4 * OO; ++m) a += h1[m] * W2[o * (4 * OO) + m];
        out[row * OO + o] = a;
    }
}

extern "C" void kernel_launch(void* const* d_in, const int* in_sizes, int n_in,
                              void* d_out, int out_size, void* d_ws, size_t ws_size,
                              hipStream_t stream) {
    const float* x    = (const float*)d_in[0];
    const float* Wih0 = (const float*)d_in[1];
    const float* Whh0 = (const float*)d_in[2];
    const float* bih0 = (const float*)d_in[3];
    const float* bhh0 = (const float*)d_in[4];
    const float* Wih1 = (const float*)d_in[5];
    const float* Whh1 = (const float*)d_in[6];
    const float* bih1 = (const float*)d_in[7];
    const float* bhh1 = (const float*)d_in[8];
    const float* Wih2 = (const float*)d_in[9];
    const float* Whh2 = (const float*)d_in[10];
    const float* bih2 = (const float*)d_in[11];
    const float* bhh2 = (const float*)d_in[12];
    const float* W1   = (const float*)d_in[13];
    const float* b1   = (const float*)d_in[14];
    const float* W2   = (const float*)d_in[15];
    const float* b2   = (const float*)d_in[16];

    float* out    = (float*)d_out;                 // [3,512,18] = 27648 floats
    float* hidden = out + NL * BB * OO;            // [3,512,33] = 50688 floats

    lstm_pipeline_kernel<<<BB, 128, 0, stream>>>(
        x, Wih0, Whh0, bih0, bhh0, Wih1, Whh1, bih1, bhh1,
        Wih2, Whh2, bih2, bhh2, hidden);

    mlp_head_kernel<<<(NL * BB + 255) / 256, 256, 0, stream>>>(
        hidden, W1, b1, W2, b2, out);
}

// Round 12
// 1049.871 us; speedup vs baseline: 1.1893x; 1.0950x over previous
//
#include <hip/hip_runtime.h>
#include <math.h>

// Problem constants (from reference)
#define TT 2048
#define BB 512
#define II 11
#define HH 33
#define NL 3
#define OO 18
#define HSLOT 48          // halves per LDS vector slot (96 B, 16B-aligned slots)

typedef _Float16 h2 __attribute__((ext_vector_type(2)));
typedef _Float16 h8 __attribute__((ext_vector_type(8)));   // 16 B -> ds_read_b128

// fast sigmoid / tanh via v_exp_f32 + v_rcp_f32 (saturate correctly at +-inf)
__device__ __forceinline__ float sigm_f(float x) {
    float e = __expf(-x);
    return __builtin_amdgcn_rcpf(1.0f + e);
}
__device__ __forceinline__ float tanh_f(float x) {
    float e = __expf(2.0f * x);
    return 1.0f - 2.0f * __builtin_amdgcn_rcpf(e + 1.0f);
}

// guarded fp32->fp16 row-slice loads (zero-pad past rem)
__device__ __forceinline__ h8 gldh8(const float* p, int k0, int rem) {
    h8 v;
    #pragma unroll
    for (int i = 0; i < 8; ++i) v[i] = (_Float16)((k0 + i < rem) ? p[k0 + i] : 0.0f);
    return v;
}
__device__ __forceinline__ h2 gldh2(const float* p, int k0, int rem) {
    h2 v;
    v.x = (_Float16)((k0 + 0 < rem) ? p[k0 + 0] : 0.0f);
    v.y = (_Float16)((k0 + 1 < rem) ? p[k0 + 1] : 0.0f);
    return v;
}

// v_dot2_f32_f16 chains: 2 MACs/op, fp32 accumulate
#define D8(a, v, w) do { \
    a = __builtin_amdgcn_fdot2((v).s01, (w).s01, a, false); \
    a = __builtin_amdgcn_fdot2((v).s23, (w).s23, a, false); \
    a = __builtin_amdgcn_fdot2((v).s45, (w).s45, a, false); \
    a = __builtin_amdgcn_fdot2((v).s67, (w).s67, a, false); } while (0)
#define D1(a, v, w) a = __builtin_amdgcn_fdot2((v), (w), a, false)

// Layer-pipelined LSTM, ONE LANE PER UNIT (no cross-lane ops), fused MLP head.
// grid = 512 blocks (one batch element each), block = 128 threads (2 waves).
//   tid < 99 : unit u = tid, l = u/33, j = u%33. The lane holds ALL weights of
//   its unit (4 gate rows x (input 34 + own-h 34) halves, packed fp16), reads
//   the layer-input vector (slot l) and own-h vector (slot l+1) from LDS
//   (broadcast reads), runs 136 fdot2, full gate nonlinearity + c/h locally.
//   Gate order: f,i dots complete first so their sigm overlaps g,o dot issue
//   (shortens the post-dot dependency tail at 1 wave/SIMD).
//   tid 99..109 : x prefetchers (11 features), 2-deep software pipeline.
// Epilogue: final h of each layer staged in LDS (fp32), then the tiny MLP head
// (gelu(h@W1^T+b1)@W2^T+b2) runs in-block -- no second dispatch.
// LDS: ping-pong buf[2][4][HSLOT] halves; one barrier per superstep; peeled
// steady state with compile-time ping-pong (R9 scheme).
__global__ __launch_bounds__(128, 1) void lstm_pipeline_kernel(
    const float* __restrict__ x,
    const float* __restrict__ Wih0, const float* __restrict__ Whh0,
    const float* __restrict__ bih0, const float* __restrict__ bhh0,
    const float* __restrict__ Wih1, const float* __restrict__ Whh1,
    const float* __restrict__ bih1, const float* __restrict__ bhh1,
    const float* __restrict__ Wih2, const float* __restrict__ Whh2,
    const float* __restrict__ bih2, const float* __restrict__ bhh2,
    const float* __restrict__ W1, const float* __restrict__ b1,
    const float* __restrict__ W2, const float* __restrict__ b2,
    float* __restrict__ hidden_out,   // [3, 512, 33]
    float* __restrict__ outp)         // [3, 512, 18]
{
    __shared__ __align__(16) _Float16 buf[2][NL + 1][HSLOT];
    __shared__ float hfin[NL][HH + 1];   // final h per layer (fp32, fused MLP)
    __shared__ float h1s[NL][4 * OO];    // MLP hidden

    const int tid = threadIdx.x;
    const int bg  = blockIdx.x;

    for (int i = tid; i < 2 * (NL + 1) * HSLOT; i += 128)
        ((_Float16*)buf)[i] = (_Float16)0.0f;

    const bool comp = (tid < 99);
    const int  u    = tid;
    const int  l    = (u < 33) ? 0 : (u < 66) ? 1 : 2;
    const int  j    = u - 33 * l;

    const int  pi   = tid - 99;
    const bool pref = (pi >= 0) && (pi < II);
    const float* xrow = x + (size_t)bg * TT * II + (pref ? pi : 0);

    // ---- per-lane weights: 4 gates x (input 34 + own 34) halves, named regs ----
    h8 z8 = {0,0,0,0,0,0,0,0};
    h2 z2 = {(_Float16)0.0f, (_Float16)0.0f};
    h8 x00=z8,x01=z8,x02=z8,x03=z8; h2 x0t=z2;   // gate i, input side (W_ih row)
    h8 x10=z8,x11=z8,x12=z8,x13=z8; h2 x1t=z2;   // gate f
    h8 x20=z8,x21=z8,x22=z8,x23=z8; h2 x2t=z2;   // gate g
    h8 x30=z8,x31=z8,x32=z8,x33=z8; h2 x3t=z2;   // gate o
    h8 h00=z8,h01=z8,h02=z8,h03=z8; h2 h0t=z2;   // gate i, own-h side (W_hh row)
    h8 h10=z8,h11=z8,h12=z8,h13=z8; h2 h1t=z2;
    h8 h20=z8,h21=z8,h22=z8,h23=z8; h2 h2t=z2;
    h8 h30=z8,h31=z8,h32=z8,h33=z8; h2 h3t=z2;
    float b0 = 0.0f, b1v = 0.0f, b2v = 0.0f, b3v = 0.0f;

    if (comp) {
        const float* bip = (l == 0) ? bih0 : (l == 1) ? bih1 : bih2;
        const float* bhp = (l == 0) ? bhh0 : (l == 1) ? bhh1 : bhh2;
        b0  = bip[0 * HH + j] + bhp[0 * HH + j];
        b1v = bip[1 * HH + j] + bhp[1 * HH + j];
        b2v = bip[2 * HH + j] + bhp[2 * HH + j];
        b3v = bip[3 * HH + j] + bhp[3 * HH + j];

        const float* Wi = (l == 0) ? Wih0 : (l == 1) ? Wih1 : Wih2;
        const float* Wh = (l == 0) ? Whh0 : (l == 1) ? Whh1 : Whh2;
        const int kin = (l == 0) ? II : HH;
        const float* r0 = Wi + (0 * HH + j) * kin;
        const float* r1 = Wi + (1 * HH + j) * kin;
        const float* r2 = Wi + (2 * HH + j) * kin;
        const float* r3 = Wi + (3 * HH + j) * kin;
        x00=gldh8(r0,0,kin); x01=gldh8(r0,8,kin); x02=gldh8(r0,16,kin); x03=gldh8(r0,24,kin); x0t=gldh2(r0,32,kin);
        x10=gldh8(r1,0,kin); x11=gldh8(r1,8,kin); x12=gldh8(r1,16,kin); x13=gldh8(r1,24,kin); x1t=gldh2(r1,32,kin);
        x20=gldh8(r2,0,kin); x21=gldh8(r2,8,kin); x22=gldh8(r2,16,kin); x23=gldh8(r2,24,kin); x2t=gldh2(r2,32,kin);
        x30=gldh8(r3,0,kin); x31=gldh8(r3,8,kin); x32=gldh8(r3,16,kin); x33=gldh8(r3,24,kin); x3t=gldh2(r3,32,kin);
        const float* s0 = Wh + (0 * HH + j) * HH;
        const float* s1 = Wh + (1 * HH + j) * HH;
        const float* s2 = Wh + (2 * HH + j) * HH;
        const float* s3 = Wh + (3 * HH + j) * HH;
        h00=gldh8(s0,0,HH); h01=gldh8(s0,8,HH); h02=gldh8(s0,16,HH); h03=gldh8(s0,24,HH); h0t=gldh2(s0,32,HH);
        h10=gldh8(s1,0,HH); h11=gldh8(s1,8,HH); h12=gldh8(s1,16,HH); h13=gldh8(s1,24,HH); h1t=gldh2(s1,32,HH);
        h20=gldh8(s2,0,HH); h21=gldh8(s2,8,HH); h22=gldh8(s2,16,HH); h23=gldh8(s2,24,HH); h2t=gldh2(s2,32,HH);
        h30=gldh8(s3,0,HH); h31=gldh8(s3,8,HH); h32=gldh8(s3,16,HH); h33=gldh8(s3,24,HH); h3t=gldh2(s3,32,HH);
    }

    __syncthreads();
    float v_next = 0.0f, v_next2 = 0.0f;
    if (pref) {
        buf[0][0][pi] = (_Float16)xrow[0];
        v_next  = xrow[II];
        v_next2 = xrow[2 * II];
    }
    __syncthreads();

    float c = 0.0f;

    // hoisted ping-pong pointers (compile-time selected in peeled steps)
    const _Float16* rin[2]  = { &buf[0][l][0],     &buf[1][l][0] };      // input vec
    const _Float16* rown[2] = { &buf[0][l + 1][0], &buf[1][l + 1][0] };  // own-h vec
    _Float16*       wrp[2]  = { &buf[0][l + 1][j], &buf[1][l + 1][j] };
    _Float16*       pxp[2]  = { &buf[0][0][pi],    &buf[1][0][pi] };

    // one superstep; all bool/int args are compile-time constants at call sites
    auto step = [&](int s, int rp, bool check, bool out, bool xload, bool xstore)
        __attribute__((always_inline)) {
        const int wp = rp ^ 1;
        if (pref) {
            if (xstore) *pxp[wp] = (_Float16)v_next;
            v_next = v_next2;
            if (xload) v_next2 = xrow[(size_t)(s + 3) * II];
        }
        const bool active = check ? (comp && (s >= l) && (s - l < TT)) : comp;
        if (active) {
            const h8* VI = (const h8*)rin[rp];
            const h8 vi0 = VI[0], vi1 = VI[1], vi2 = VI[2], vi3 = VI[3];
            const h2 vit = *(const h2*)(rin[rp] + 32);
            const h8* VO = (const h8*)rown[rp];
            const h8 vo0 = VO[0], vo1 = VO[1], vo2 = VO[2], vo3 = VO[3];
            const h2 vot = *(const h2*)(rown[rp] + 32);

            // ---- phase A: gates f (a1) and i (a0) -- dots then sigm early ----
            float a0 = b0, a1 = b1v;
            D8(a1, vi0, x10); D8(a0, vi0, x00);
            D8(a1, vi1, x11); D8(a0, vi1, x01);
            D8(a1, vi2, x12); D8(a0, vi2, x02);
            D8(a1, vi3, x13); D8(a0, vi3, x03);
            D1(a1, vit, x1t); D1(a0, vit, x0t);
            D8(a1, vo0, h10); D8(a0, vo0, h00);
            D8(a1, vo1, h11); D8(a0, vo1, h01);
            D8(a1, vo2, h12); D8(a0, vo2, h02);
            D8(a1, vo3, h13); D8(a0, vo3, h03);
            D1(a1, vot, h1t); D1(a0, vot, h0t);
            const float fg = sigm_f(a1);   // trans overlaps phase-B dot issue
            const float ig = sigm_f(a0);

            // ---- phase B: gates g (a2) and o (a3) ----
            float a2 = b2v, a3 = b3v;
            D8(a2, vi0, x20); D8(a3, vi0, x30);
            D8(a2, vi1, x21); D8(a3, vi1, x31);
            D8(a2, vi2, x22); D8(a3, vi2, x32);
            D8(a2, vi3, x23); D8(a3, vi3, x33);
            D1(a2, vit, x2t); D1(a3, vit, x3t);
            D8(a2, vo0, h20); D8(a3, vo0, h30);
            D8(a2, vo1, h21); D8(a3, vo1, h31);
            D8(a2, vo2, h22); D8(a3, vo2, h32);
            D8(a2, vo3, h23); D8(a3, vo3, h33);
            D1(a2, vot, h2t); D1(a3, vot, h3t);

            const float gg = tanh_f(a2);
            const float og = sigm_f(a3);
            c = __builtin_fmaf(fg, c, ig * gg);
            const float hnew = og * tanh_f(c);

            *wrp[wp] = (_Float16)hnew;
            if (out && (s - l == TT - 1)) {
                hidden_out[((size_t)l * BB + bg) * HH + j] = hnew;
                hfin[l][j] = hnew;
            }
        }
        __syncthreads();
    };

    // prologue (pipeline fill, masked)
    step(0, 0, true, false, true, true);
    step(1, 1, true, false, true, true);
    // steady state: s = 2..2043 as constant-rp pairs (no checks, no outputs)
    for (int s = 2; s < TT - 4; s += 2) {
        step(s,     0, false, false, true, true);
        step(s + 1, 1, false, false, true, true);
    }
    // tail of steady state + epilogue (drain + final-h outputs)
    step(TT - 4, 0, false, false, true,  true);    // s=2044 (last x load)
    step(TT - 3, 1, false, false, false, true);    // s=2045
    step(TT - 2, 0, false, false, false, true);    // s=2046 (stores x[2047])
    step(TT - 1, 1, false, true,  false, false);   // s=2047: l0 writes hT
    step(TT,     0, true,  true,  false, false);   // s=2048: l1 writes hT
    step(TT + 1, 1, true,  true,  false, false);   // s=2049: l2 writes hT

    // ---- fused MLP head (hfin visible after the last step's barrier) ----
    // h1 = gelu_exact(hfin @ W1^T + b1) [3,72]; out = h1 @ W2^T + b2 [3,18]
    if (tid < 4 * OO) {                   // 72 threads x 3 layers
        #pragma unroll
        for (int ml = 0; ml < NL; ++ml) {
            float a = b1[tid];
            #pragma unroll
            for (int k = 0; k < HH; ++k) a += hfin[ml][k] * W1[tid * HH + k];
            h1s[ml][tid] = 0.5f * a * (1.0f + erff(a * 0.70710678118654752f));
        }
    }
    __syncthreads();
    if (tid < NL * OO) {                  // 54 threads
        const int ol = tid / OO, o = tid % OO;
        float a = b2[o];
        #pragma unroll
        for (int m = 0; m < 4 * OO; ++m) a += h1s[ol][m] * W2[o * (4 * OO) + m];
        outp[((size_t)ol * BB + bg) * OO + o] = a;
    }
}

extern "C" void kernel_launch(void* const* d_in, const int* in_sizes, int n_in,
                              void* d_out, int out_size, void* d_ws, size_t ws_size,
                              hipStream_t stream) {
    const float* x    = (const float*)d_in[0];
    const float* Wih0 = (const float*)d_in[1];
    const float* Whh0 = (const float*)d_in[2];
    const float* bih0 = (const float*)d_in[3];
    const float* bhh0 = (const float*)d_in[4];
    const float* Wih1 = (const float*)d_in[5];
    const float* Whh1 = (const float*)d_in[6];
    const float* bih1 = (const float*)d_in[7];
    const float* bhh1 = (const float*)d_in[8];
    const float* Wih2 = (const float*)d_in[9];
    const float* Whh2 = (const float*)d_in[10];
    const float* bih2 = (const float*)d_in[11];
    const float* bhh2 = (const float*)d_in[12];
    const float* W1   = (const float*)d_in[13];
    const float* b1   = (const float*)d_in[14];
    const float* W2   = (const float*)d_in[15];
    const float* b2   = (const float*)d_in[16];

    float* out    = (float*)d_out;                 // [3,512,18] = 27648 floats
    float* hidden = out + NL * BB * OO;            // [3,512,33] = 50688 floats

    lstm_pipeline_kernel<<<BB, 128, 0, stream>>>(
        x, Wih0, Whh0, bih0, bhh0, Wih1, Whh1, bih1, bhh1,
        Wih2, Whh2, bih2, bhh2, W1, b1, W2, b2, hidden, out);
}